// Round 3
// baseline (5152.624 us; speedup 1.0000x reference)
//
#include <hip/hip_runtime.h>
#include <math.h>

#define TT 512
#define DD 1024
#define BB 32
#define G3D (3*DD)

typedef _Float16 f16;
typedef _Float16 f16x2 __attribute__((ext_vector_type(2)));
typedef _Float16 f16x4 __attribute__((ext_vector_type(4)));
typedef _Float16 f16x8 __attribute__((ext_vector_type(8)));
typedef float f32x4 __attribute__((ext_vector_type(4)));
typedef unsigned long long u64;

// ---------------------------------------------------------------- kernel A
__global__ void k_convert(const float* __restrict__ Wih, const float* __restrict__ Whh,
                          f16* __restrict__ Wih16, f16* __restrict__ Whh16,
                          f16* __restrict__ h16, unsigned int* __restrict__ bar) {
    int idx = blockIdx.x * 256 + threadIdx.x;
    int n = G3D * DD;
    if (idx < n) {
        Wih16[idx] = (f16)Wih[idx];
        Whh16[idx] = (f16)Whh[idx];
    }
    if (idx < 2 * BB * DD) h16[idx] = (f16)0.f;
    if (idx == 0) *bar = 0u;
}

// ---------------------------------------------------------------- kernel B
// GI[16384][3072] = h_enc[16384][1024] * Wih^T + b_ih  (fp16 out)
#define BM 128
#define BN 128
#define BK 32
#define LDA 40

__global__ __launch_bounds__(256) void k_pregemm(
    const float* __restrict__ X,
    const f16*   __restrict__ W16,
    const float* __restrict__ bih,
    f16* __restrict__ GI)
{
    __shared__ f16 As[BM * LDA];
    __shared__ f16 Bs[BN * LDA];
    const int tid  = threadIdx.x;
    const int lane = tid & 63;
    const int wave = tid >> 6;
    const int wr = wave >> 1, wc = wave & 1;
    const int m0 = blockIdx.y * BM;
    const int n0 = blockIdx.x * BN;
    const int mfrag = lane & 15;
    const int qfrag = lane >> 4;

    f32x4 acc[4][4] = {};

    for (int kt = 0; kt < DD; kt += BK) {
        __syncthreads();
        {
            int row = tid >> 3;
            int c   = tid & 7;
            #pragma unroll
            for (int p = 0; p < 4; ++p) {
                int r = row + p * 32;
                float4 v = *(const float4*)(X + (size_t)(m0 + r) * DD + kt + c * 4);
                f16x4 hv = { (f16)v.x, (f16)v.y, (f16)v.z, (f16)v.w };
                *(f16x4*)(As + r * LDA + c * 4) = hv;
            }
        }
        {
            int row = tid >> 2;
            int c   = tid & 3;
            #pragma unroll
            for (int p = 0; p < 2; ++p) {
                int r = row + p * 64;
                f16x8 v = *(const f16x8*)(W16 + (size_t)(n0 + r) * DD + kt + c * 8);
                *(f16x8*)(Bs + r * LDA + c * 8) = v;
            }
        }
        __syncthreads();
        f16x8 af[4], bf[4];
        #pragma unroll
        for (int i = 0; i < 4; ++i)
            af[i] = *(const f16x8*)(As + (wr * 64 + i * 16 + mfrag) * LDA + qfrag * 8);
        #pragma unroll
        for (int j = 0; j < 4; ++j)
            bf[j] = *(const f16x8*)(Bs + (wc * 64 + j * 16 + mfrag) * LDA + qfrag * 8);
        #pragma unroll
        for (int i = 0; i < 4; ++i)
            #pragma unroll
            for (int j = 0; j < 4; ++j)
                acc[i][j] = __builtin_amdgcn_mfma_f32_16x16x32_f16(af[i], bf[j], acc[i][j], 0, 0, 0);
    }
    #pragma unroll
    for (int j = 0; j < 4; ++j) {
        int col = n0 + wc * 64 + j * 16 + mfrag;
        float bias = bih[col];
        #pragma unroll
        for (int i = 0; i < 4; ++i) {
            int rowb = m0 + wr * 64 + i * 16 + qfrag * 4;
            #pragma unroll
            for (int r = 0; r < 4; ++r)
                GI[(size_t)(rowb + r) * G3D + col] = (f16)(acc[i][j][r] + bias);
        }
    }
}

// ---------------------------------------------------------------- kernel C
// Persistent recurrent kernel: 32 blocks x 512 threads (8 waves).
// wave w -> (colhalf ch = w&1, K-quarter kq = w>>1). Per-lane W_hh = 96 VGPRs,
// loaded via relaxed atomic u64 (non-rematerializable -> register-pinned).
__global__ __launch_bounds__(512, 2) void k_gru(
    const f16* __restrict__ Whh16,   // [3072][1024]
    const f16* __restrict__ GI,      // [16384][3072]
    const float* __restrict__ bhh,   // [3072]
    float* __restrict__ out,         // [32][512][1024] fp32
    f16* __restrict__ h16,           // [2][32][1024] exchange
    unsigned int* __restrict__ bar)
{
    __shared__ float red[4][3][32][36];   // stride 36 => <=2-way bank aliasing
    __shared__ float h32[32][34];
    __shared__ float bh_s[3][32];

    const int tid  = threadIdx.x;
    const int lane = tid & 63;
    const int wv   = tid >> 6;        // 0..7
    const int ch   = wv & 1;          // col half (16 cols)
    const int kq   = wv >> 1;         // K quarter (256)
    const int j0   = blockIdx.x * 32;
    const int mfrag = lane & 15;
    const int qk    = lane >> 4;      // 0..3

    for (int i = tid; i < 32 * 34; i += 512) ((float*)h32)[i] = 0.f;
    if (tid < 96) bh_s[tid >> 5][tid & 31] = bhh[(tid >> 5) * DD + j0 + (tid & 31)];

    // W_hh fragments: wf[gate][k-iter], 24 x f16x8 = 96 VGPRs, atomic-pinned.
    const u64* wp = (const u64*)Whh16;
    f16x8 wf[3][8];
    #pragma unroll
    for (int g = 0; g < 3; ++g)
        #pragma unroll
        for (int it = 0; it < 8; ++it) {
            size_t idx = (((size_t)(g * DD + j0 + ch * 16 + mfrag)) * DD
                          + kq * 256 + it * 32 + qk * 8) >> 2;
            union { u64 u[2]; f16x8 v; } tmp;
            tmp.u[0] = __hip_atomic_load(wp + idx,     __ATOMIC_RELAXED, __HIP_MEMORY_SCOPE_AGENT);
            tmp.u[1] = __hip_atomic_load(wp + idx + 1, __ATOMIC_RELAXED, __HIP_MEMORY_SCOPE_AGENT);
            wf[g][it] = tmp.v;
        }
    __syncthreads();

    const int bg = tid >> 4;          // combine: batch row 0..31
    const int c2 = (tid & 15) * 2;    // combine: col pair

    // prefetch gi for t=0
    f16x2 giv[3], givn[3];
    #pragma unroll
    for (int g = 0; g < 3; ++g)
        giv[g] = *(const f16x2*)(GI + (size_t)(bg * TT + 0) * G3D + g * DD + j0 + c2);

    for (int t = 0; t < TT; ++t) {
        const int par = t & 1;

        // A-fragments of h: relaxed agent atomic 8B loads (LLC-coherent)
        const u64* hb = (const u64*)(h16 + (size_t)par * BB * DD);
        f16x8 af[8][2];
        #pragma unroll
        for (int it = 0; it < 8; ++it)
            #pragma unroll
            for (int rt = 0; rt < 2; ++rt) {
                int base = ((rt * 16 + mfrag) * DD + kq * 256 + it * 32 + qk * 8) >> 2;
                union { u64 u[2]; f16x8 v; } tmp;
                tmp.u[0] = __hip_atomic_load(hb + base,     __ATOMIC_RELAXED, __HIP_MEMORY_SCOPE_AGENT);
                tmp.u[1] = __hip_atomic_load(hb + base + 1, __ATOMIC_RELAXED, __HIP_MEMORY_SCOPE_AGENT);
                af[it][rt] = tmp.v;
            }

        // prefetch gi for t+1 (off critical path; covers HBM-miss tail)
        {
            int tn = (t + 1 < TT) ? t + 1 : t;
            #pragma unroll
            for (int g = 0; g < 3; ++g)
                givn[g] = *(const f16x2*)(GI + (size_t)(bg * TT + tn) * G3D + g * DD + j0 + c2);
        }

        f32x4 acc[3][2] = {};
        #pragma unroll
        for (int it = 0; it < 8; ++it)
            #pragma unroll
            for (int g = 0; g < 3; ++g)
                #pragma unroll
                for (int rt = 0; rt < 2; ++rt)
                    acc[g][rt] = __builtin_amdgcn_mfma_f32_16x16x32_f16(
                        af[it][rt], wf[g][it], acc[g][rt], 0, 0, 0);

        // dump K-partials. C/D: col=lane&15, row=(lane>>4)*4+reg
        #pragma unroll
        for (int g = 0; g < 3; ++g)
            #pragma unroll
            for (int rt = 0; rt < 2; ++rt)
                #pragma unroll
                for (int r = 0; r < 4; ++r)
                    red[kq][g][rt * 16 + qk * 4 + r][ch * 16 + mfrag] = acc[g][rt][r];
        __syncthreads();

        // combine: thread -> batch bg, cols {c2, c2+1}
        {
            float2 gr = make_float2(0.f, 0.f), gz = gr, gn = gr;
            #pragma unroll
            for (int q = 0; q < 4; ++q) {
                float2 vr = *(const float2*)&red[q][0][bg][c2];
                float2 vz = *(const float2*)&red[q][1][bg][c2];
                float2 vn = *(const float2*)&red[q][2][bg][c2];
                gr.x += vr.x; gr.y += vr.y;
                gz.x += vz.x; gz.y += vz.y;
                gn.x += vn.x; gn.y += vn.y;
            }
            float hnew[2];
            #pragma unroll
            for (int cc = 0; cc < 2; ++cc) {
                float ghr = cc ? gr.y : gr.x;
                float ghz = cc ? gz.y : gz.x;
                float ghn = cc ? gn.y : gn.x;
                float pr = (float)giv[0][cc] + ghr + bh_s[0][c2 + cc];
                float pz = (float)giv[1][cc] + ghz + bh_s[1][c2 + cc];
                float r  = 1.f / (1.f + __expf(-pr));
                float z  = 1.f / (1.f + __expf(-pz));
                float pn = (float)giv[2][cc] + r * (ghn + bh_s[2][c2 + cc]);
                float e  = __expf(-2.f * fabsf(pn));
                float tn = (1.f - e) / (1.f + e);
                tn = pn < 0.f ? -tn : tn;
                float hold = h32[bg][c2 + cc];
                float hn2 = tn + z * (hold - tn);
                h32[bg][c2 + cc] = hn2;
                hnew[cc] = hn2;
            }
            *(float2*)(out + (size_t)(bg * TT + t) * DD + j0 + c2) = make_float2(hnew[0], hnew[1]);
            union { unsigned int u; f16x2 h; } pk;
            pk.h[0] = (f16)hnew[0]; pk.h[1] = (f16)hnew[1];
            unsigned int* hp = (unsigned int*)h16;
            __hip_atomic_store(hp + (((par ^ 1) * BB * DD + bg * DD + j0 + c2) >> 1), pk.u,
                               __ATOMIC_RELAXED, __HIP_MEMORY_SCOPE_AGENT);
        }

        __builtin_amdgcn_s_waitcnt(0x0F70);   // vmcnt(0): h16 stores drained
        __syncthreads();
        if (tid == 0) {
            __hip_atomic_fetch_add(bar, 1u, __ATOMIC_RELAXED, __HIP_MEMORY_SCOPE_AGENT);
            unsigned int target = 32u * (unsigned)(t + 1);
            while (__hip_atomic_load(bar, __ATOMIC_RELAXED, __HIP_MEMORY_SCOPE_AGENT) < target)
                __builtin_amdgcn_s_sleep(1);
        }
        __syncthreads();

        giv[0] = givn[0]; giv[1] = givn[1]; giv[2] = givn[2];
    }
}

// ---------------------------------------------------------------- launch
extern "C" void kernel_launch(void* const* d_in, const int* in_sizes, int n_in,
                              void* d_out, int out_size, void* d_ws, size_t ws_size,
                              hipStream_t stream) {
    const float* h_enc = (const float*)d_in[0];
    const float* Wih   = (const float*)d_in[1];
    const float* Whh   = (const float*)d_in[2];
    const float* bih   = (const float*)d_in[3];
    const float* bhh   = (const float*)d_in[4];
    float* out = (float*)d_out;

    char* ws = (char*)d_ws;
    f16* GI     = (f16*)(ws);
    f16* Wih16  = (f16*)(ws + 100663296);
    f16* Whh16  = (f16*)(ws + 106954752);
    f16* h16    = (f16*)(ws + 113246208);
    unsigned int* bar = (unsigned int*)(ws + 113377280);

    hipLaunchKernelGGL(k_convert, dim3(12288), dim3(256), 0, stream,
                       Wih, Whh, Wih16, Whh16, h16, bar);
    hipLaunchKernelGGL(k_pregemm, dim3(24, 128), dim3(256), 0, stream,
                       h_enc, Wih16, bih, GI);
    hipLaunchKernelGGL(k_gru, dim3(32), dim3(512), 0, stream,
                       Whh16, GI, bhh, out, h16, bar);
}

// Round 4
// 3306.390 us; speedup vs baseline: 1.5584x; 1.5584x over previous
//
#include <hip/hip_runtime.h>
#include <math.h>

#define TT 512
#define DD 1024
#define BB 32
#define G3D (3*DD)
#define NBLK 64          // k_gru blocks; each owns 16 h-columns

typedef _Float16 f16;
typedef _Float16 f16x2 __attribute__((ext_vector_type(2)));
typedef _Float16 f16x4 __attribute__((ext_vector_type(4)));
typedef _Float16 f16x8 __attribute__((ext_vector_type(8)));
typedef float f32x4 __attribute__((ext_vector_type(4)));
typedef unsigned long long u64;

// ---------------------------------------------------------------- kernel A
// Convert weights fp32->fp16, zero h exchange buffers + per-block flags.
__global__ void k_convert(const float* __restrict__ Wih, const float* __restrict__ Whh,
                          f16* __restrict__ Wih16, f16* __restrict__ Whh16,
                          f16* __restrict__ h16, unsigned int* __restrict__ flags) {
    int idx = blockIdx.x * 256 + threadIdx.x;
    int n = G3D * DD;
    if (idx < n) {
        Wih16[idx] = (f16)Wih[idx];
        Whh16[idx] = (f16)Whh[idx];
    }
    if (idx < 2 * BB * DD) h16[idx] = (f16)0.f;
    if (idx < NBLK * 32) flags[idx] = 0u;     // 64 flags spaced 32 dwords
}

// ---------------------------------------------------------------- kernel B
// GI[16384][3072] = h_enc[16384][1024] * Wih^T + b_ih  (fp16 out)
#define BM 128
#define BN 128
#define BK 32
#define LDA 40

__global__ __launch_bounds__(256) void k_pregemm(
    const float* __restrict__ X,
    const f16*   __restrict__ W16,
    const float* __restrict__ bih,
    f16* __restrict__ GI)
{
    __shared__ f16 As[BM * LDA];
    __shared__ f16 Bs[BN * LDA];
    const int tid  = threadIdx.x;
    const int lane = tid & 63;
    const int wave = tid >> 6;
    const int wr = wave >> 1, wc = wave & 1;
    const int m0 = blockIdx.y * BM;
    const int n0 = blockIdx.x * BN;
    const int mfrag = lane & 15;
    const int qfrag = lane >> 4;

    f32x4 acc[4][4] = {};

    for (int kt = 0; kt < DD; kt += BK) {
        __syncthreads();
        {
            int row = tid >> 3;
            int c   = tid & 7;
            #pragma unroll
            for (int p = 0; p < 4; ++p) {
                int r = row + p * 32;
                float4 v = *(const float4*)(X + (size_t)(m0 + r) * DD + kt + c * 4);
                f16x4 hv = { (f16)v.x, (f16)v.y, (f16)v.z, (f16)v.w };
                *(f16x4*)(As + r * LDA + c * 4) = hv;
            }
        }
        {
            int row = tid >> 2;
            int c   = tid & 3;
            #pragma unroll
            for (int p = 0; p < 2; ++p) {
                int r = row + p * 64;
                f16x8 v = *(const f16x8*)(W16 + (size_t)(n0 + r) * DD + kt + c * 8);
                *(f16x8*)(Bs + r * LDA + c * 8) = v;
            }
        }
        __syncthreads();
        f16x8 af[4], bf[4];
        #pragma unroll
        for (int i = 0; i < 4; ++i)
            af[i] = *(const f16x8*)(As + (wr * 64 + i * 16 + mfrag) * LDA + qfrag * 8);
        #pragma unroll
        for (int j = 0; j < 4; ++j)
            bf[j] = *(const f16x8*)(Bs + (wc * 64 + j * 16 + mfrag) * LDA + qfrag * 8);
        #pragma unroll
        for (int i = 0; i < 4; ++i)
            #pragma unroll
            for (int j = 0; j < 4; ++j)
                acc[i][j] = __builtin_amdgcn_mfma_f32_16x16x32_f16(af[i], bf[j], acc[i][j], 0, 0, 0);
    }
    #pragma unroll
    for (int j = 0; j < 4; ++j) {
        int col = n0 + wc * 64 + j * 16 + mfrag;
        float bias = bih[col];
        #pragma unroll
        for (int i = 0; i < 4; ++i) {
            int rowb = m0 + wr * 64 + i * 16 + qfrag * 4;
            #pragma unroll
            for (int r = 0; r < 4; ++r)
                GI[(size_t)(rowb + r) * G3D + col] = (f16)(acc[i][j][r] + bias);
        }
    }
}

// ---------------------------------------------------------------- kernel C
// Persistent recurrent kernel: 64 blocks x 256 threads (4 waves = K-quarters).
// Block bid owns h columns [bid*16, bid*16+16). Its W_hh slice (48 rows x 1024,
// 99 KB) lives in LDS -> ds_read_b128 B-fragments every step (no global
// weight traffic). Cross-block sync: per-block epoch flags on separate cache
// lines (parallel fan-in), LLC-coherent relaxed atomics (sc0 sc1), no L2
// wbl2/inv anywhere.
#define WROW 1032    // LDS row stride in halves (1024 + 8 pad; 2064 B, 16B-mult)

__global__ __launch_bounds__(256, 1) void k_gru(
    const f16* __restrict__ Whh16,   // [3072][1024]
    const f16* __restrict__ GI,      // [16384][3072]
    const float* __restrict__ bhh,   // [3072]
    float* __restrict__ out,         // [32][512][1024] fp32
    f16* __restrict__ h16,           // [2][32][1024] exchange
    unsigned int* __restrict__ flags)// [64] epoch flags, 32-dword spacing
{
    __shared__ f16 Ws[48 * WROW];           // 99072 B
    __shared__ float red[4][3][32][20];     // 30720 B, col-pad 16->20
    __shared__ float h32[32][18];
    __shared__ float bh_s[3][16];

    const int tid  = threadIdx.x;
    const int lane = tid & 63;
    const int kq   = tid >> 6;        // wave id = K quarter (256)
    const int bid  = blockIdx.x;
    const int j0   = bid * 16;
    const int mfrag = lane & 15;
    const int qk    = lane >> 4;      // 0..3

    // stage W_hh slice into LDS: LDS row r -> gate r>>4, col n=r&15
    for (int i = tid; i < 48 * 128; i += 256) {
        int r = i >> 7, c = i & 127;
        int grow = (r >> 4) * DD + j0 + (r & 15);
        *(f16x8*)(Ws + r * WROW + c * 8) =
            *(const f16x8*)(Whh16 + (size_t)grow * DD + c * 8);
    }
    for (int i = tid; i < 32 * 18; i += 256) ((float*)h32)[i] = 0.f;
    if (tid < 48) bh_s[tid >> 4][tid & 15] = bhh[(tid >> 4) * DD + j0 + (tid & 15)];
    __syncthreads();

    const int bg = tid >> 3;          // combine: batch row 0..31
    const int c2 = (tid & 7) * 2;     // combine: col pair 0..14

    // prefetch gi for t=0
    f16x2 giv[3], givn[3];
    #pragma unroll
    for (int g = 0; g < 3; ++g)
        giv[g] = *(const f16x2*)(GI + (size_t)bg * TT * G3D + g * DD + j0 + c2);

    for (int t = 0; t < TT; ++t) {
        const int par = t & 1;

        // A-fragments of h: relaxed agent atomic 8B loads (LLC-coherent)
        const u64* hb = (const u64*)(h16 + (size_t)par * BB * DD);
        f16x8 af[8][2];
        #pragma unroll
        for (int it = 0; it < 8; ++it)
            #pragma unroll
            for (int rt = 0; rt < 2; ++rt) {
                int base = ((rt * 16 + mfrag) * DD + kq * 256 + it * 32 + qk * 8) >> 2;
                union { u64 u[2]; f16x8 v; } tmp;
                tmp.u[0] = __hip_atomic_load(hb + base,     __ATOMIC_RELAXED, __HIP_MEMORY_SCOPE_AGENT);
                tmp.u[1] = __hip_atomic_load(hb + base + 1, __ATOMIC_RELAXED, __HIP_MEMORY_SCOPE_AGENT);
                af[it][rt] = tmp.v;
            }

        // prefetch gi for t+1 (off critical path)
        {
            int tn = (t + 1 < TT) ? t + 1 : t;
            #pragma unroll
            for (int g = 0; g < 3; ++g)
                givn[g] = *(const f16x2*)(GI + ((size_t)bg * TT + tn) * G3D + g * DD + j0 + c2);
        }

        // MFMA: B-frags streamed from LDS (ds_read_b128), weights stay on-CU
        f32x4 acc[3][2] = {};
        #pragma unroll
        for (int it = 0; it < 8; ++it) {
            f16x8 bf[3];
            #pragma unroll
            for (int g = 0; g < 3; ++g)
                bf[g] = *(const f16x8*)(Ws + (g * 16 + mfrag) * WROW + kq * 256 + it * 32 + qk * 8);
            #pragma unroll
            for (int g = 0; g < 3; ++g)
                #pragma unroll
                for (int rt = 0; rt < 2; ++rt)
                    acc[g][rt] = __builtin_amdgcn_mfma_f32_16x16x32_f16(
                        af[it][rt], bf[g], acc[g][rt], 0, 0, 0);
        }

        // dump K-partials. C/D: col=lane&15, row=(lane>>4)*4+reg
        #pragma unroll
        for (int g = 0; g < 3; ++g)
            #pragma unroll
            for (int rt = 0; rt < 2; ++rt)
                #pragma unroll
                for (int r = 0; r < 4; ++r)
                    red[kq][g][rt * 16 + qk * 4 + r][mfrag] = acc[g][rt][r];
        __syncthreads();

        // combine: thread -> batch bg, cols {c2, c2+1}
        {
            float2 gr = make_float2(0.f, 0.f), gz = gr, gn = gr;
            #pragma unroll
            for (int q = 0; q < 4; ++q) {
                float2 vr = *(const float2*)&red[q][0][bg][c2];
                float2 vz = *(const float2*)&red[q][1][bg][c2];
                float2 vn = *(const float2*)&red[q][2][bg][c2];
                gr.x += vr.x; gr.y += vr.y;
                gz.x += vz.x; gz.y += vz.y;
                gn.x += vn.x; gn.y += vn.y;
            }
            float hnew[2];
            #pragma unroll
            for (int cc = 0; cc < 2; ++cc) {
                float ghr = cc ? gr.y : gr.x;
                float ghz = cc ? gz.y : gz.x;
                float ghn = cc ? gn.y : gn.x;
                float pr = (float)giv[0][cc] + ghr + bh_s[0][c2 + cc];
                float pz = (float)giv[1][cc] + ghz + bh_s[1][c2 + cc];
                float r  = 1.f / (1.f + __expf(-pr));
                float z  = 1.f / (1.f + __expf(-pz));
                float pn = (float)giv[2][cc] + r * (ghn + bh_s[2][c2 + cc]);
                float e  = __expf(-2.f * fabsf(pn));
                float tn = (1.f - e) / (1.f + e);
                tn = pn < 0.f ? -tn : tn;
                float hold = h32[bg][c2 + cc];
                float hn2 = tn + z * (hold - tn);
                h32[bg][c2 + cc] = hn2;
                hnew[cc] = hn2;
            }
            // publish h16 first (critical path), then out (off critical path)
            union { unsigned int u; f16x2 h; } pk;
            pk.h[0] = (f16)hnew[0]; pk.h[1] = (f16)hnew[1];
            unsigned int* hp = (unsigned int*)h16;
            __hip_atomic_store(hp + (((par ^ 1) * BB * DD + bg * DD + j0 + c2) >> 1), pk.u,
                               __ATOMIC_RELAXED, __HIP_MEMORY_SCOPE_AGENT);
            *(float2*)(out + ((size_t)bg * TT + t) * DD + j0 + c2) = make_float2(hnew[0], hnew[1]);
        }

        // release: drain stores, then parallel per-block flag fan-in/out
        __builtin_amdgcn_s_waitcnt(0x0F70);   // vmcnt(0)
        __syncthreads();                      // all waves drained
        if (tid < NBLK) {
            if (tid == 0)
                __hip_atomic_store(flags + bid * 32, (unsigned)(t + 1),
                                   __ATOMIC_RELAXED, __HIP_MEMORY_SCOPE_AGENT);
            while (__hip_atomic_load(flags + tid * 32, __ATOMIC_RELAXED,
                                     __HIP_MEMORY_SCOPE_AGENT) < (unsigned)(t + 1))
                __builtin_amdgcn_s_sleep(1);
        }
        __syncthreads();

        giv[0] = givn[0]; giv[1] = givn[1]; giv[2] = givn[2];
    }
}

// ---------------------------------------------------------------- launch
extern "C" void kernel_launch(void* const* d_in, const int* in_sizes, int n_in,
                              void* d_out, int out_size, void* d_ws, size_t ws_size,
                              hipStream_t stream) {
    const float* h_enc = (const float*)d_in[0];
    const float* Wih   = (const float*)d_in[1];
    const float* Whh   = (const float*)d_in[2];
    const float* bih   = (const float*)d_in[3];
    const float* bhh   = (const float*)d_in[4];
    float* out = (float*)d_out;

    char* ws = (char*)d_ws;
    // ws layout: GI 100663296 | Wih16 6291456 | Whh16 6291456 | h16 131072 | flags 8192
    f16* GI     = (f16*)(ws);
    f16* Wih16  = (f16*)(ws + 100663296);
    f16* Whh16  = (f16*)(ws + 106954752);
    f16* h16    = (f16*)(ws + 113246208);
    unsigned int* flags = (unsigned int*)(ws + 113377280);

    hipLaunchKernelGGL(k_convert, dim3(12288), dim3(256), 0, stream,
                       Wih, Whh, Wih16, Whh16, h16, flags);
    hipLaunchKernelGGL(k_pregemm, dim3(24, 128), dim3(256), 0, stream,
                       h_enc, Wih16, bih, GI);
    hipLaunchKernelGGL(k_gru, dim3(NBLK), dim3(256), 0, stream,
                       Whh16, GI, bhh, out, h16, flags);
}